// Round 4
// baseline (3896.856 us; speedup 1.0000x reference)
//
#include <hip/hip_runtime.h>

// B=131072 indep LSTMs, T=40, H=40, in-dim 1, FC C=4 + argmax.
// R4: R3 was grid-limited (2048 waves = 2/SIMD, VALUBusy 71%, occ 20%).
// Split each sample's 40 units across 2 waves of a block (j stays
// wave-uniform -> weights remain scalar loads). 4096 waves = 4/SIMD.
// h exchanged via 10KB LDS ([j*64+s] -> bank=s%32, conflict-free),
// 2 barriers/t-step; c in private LDS slice. 20KB LDS = 8 blocks/CU.

#define B_ 131072
#define T_ 40
#define H_ 40
#define C_ 4
#define BLK 128          // 2 waves
#define SMP 64           // samples per block
#define JPW 20           // units per wave

__device__ __forceinline__ float fexp2f(float v) { return __builtin_amdgcn_exp2f(v); }
__device__ __forceinline__ float frcpf(float v)  { return __builtin_amdgcn_rcpf(v); }

// sigmoid(x) = 1/(1+2^(-x*log2 e)); exact tails 0/1
__device__ __forceinline__ float sigmf(float v) {
    return frcpf(1.0f + fexp2f(-1.44269504088896340736f * v));
}
// tanh(x) = 1 - 2/(1+2^(2x*log2 e)); exact tails +/-1
__device__ __forceinline__ float tanhf_(float v) {
    return 1.0f - 2.0f * frcpf(1.0f + fexp2f(2.88539008177792681472f * v));
}

#define RPT(M) M(0) M(1) M(2) M(3) M(4) M(5) M(6) M(7) M(8) M(9) \
               M(10) M(11) M(12) M(13) M(14) M(15) M(16) M(17) M(18) M(19) \
               M(20) M(21) M(22) M(23) M(24) M(25) M(26) M(27) M(28) M(29) \
               M(30) M(31) M(32) M(33) M(34) M(35) M(36) M(37) M(38) M(39)

__global__ __launch_bounds__(BLK, 4)
void lstm_fused_kernel(const float* __restrict__ x,
                       const float* __restrict__ W_ih,   // (160,1)
                       const float* __restrict__ W_hh,   // (160,40) row-major
                       const float* __restrict__ b_ih,   // (160,)
                       const float* __restrict__ b_hh,   // (160,)
                       const float* __restrict__ W_fc,   // (4,40) row-major
                       const float* __restrict__ b_fc,   // (4,)
                       float* __restrict__ out)          // [B*4 logits][B argmax-as-float]
{
    __shared__ float cbuf[H_ * SMP];   // c[j]    at [j*64 + s]
    __shared__ float hbuf[H_ * SMP];   // h_new[j] at [j*64 + s]

    const int tid = threadIdx.x;
    const int wv  = tid >> 6;          // 0 or 1
    const int s   = tid & 63;          // sample within block
    const int jbase = wv * JPW;        // this wave's unit range
    const int b = blockIdx.x * SMP + s;
    const float* xr = x + (long)b * T_;

    float* cb  = cbuf + jbase * SMP + s;   // cb[u*SMP],  u in [0,20)
    float* hbw = hbuf + jbase * SMP + s;   // write slice
    float* hrd = hbuf + s;                 // read slice, hrd[j*SMP]

    // full hidden state in named regs (both waves keep all 40)
#define DECLH(i) float h##i = 0.0f;
    RPT(DECLH)
#undef DECLH

    // zero own cell-state slice
#pragma unroll
    for (int u = 0; u < JPW; ++u) cb[u * SMP] = 0.0f;

    float xt = xr[0];

#pragma unroll 1
    for (int t = 0; t < T_; ++t) {
        const int tn = (t + 1 < T_) ? (t + 1) : (T_ - 1);
        const float xnext = xr[tn];    // prefetch next scalar input

#pragma unroll 1
        for (int u = 0; u < JPW; ++u) {
            const int j = jbase + u;   // wave-uniform -> scalar weight loads
            const float* W0 = W_hh + j * H_;
            const float* W1 = W0 + 40 * H_;
            const float* W2 = W0 + 80 * H_;
            const float* W3 = W0 + 120 * H_;
            float a0 = fmaf(xt, W_ih[j],       b_ih[j]       + b_hh[j]);
            float a1 = fmaf(xt, W_ih[40 + j],  b_ih[40 + j]  + b_hh[40 + j]);
            float a2 = fmaf(xt, W_ih[80 + j],  b_ih[80 + j]  + b_hh[80 + j]);
            float a3 = fmaf(xt, W_ih[120 + j], b_ih[120 + j] + b_hh[120 + j]);
#define MACK(k) \
            a0 = fmaf(h##k, W0[k], a0); \
            a1 = fmaf(h##k, W1[k], a1); \
            a2 = fmaf(h##k, W2[k], a2); \
            a3 = fmaf(h##k, W3[k], a3);
            RPT(MACK)
#undef MACK
            const float ig = sigmf(a0);
            const float fg = sigmf(a1);
            const float gv = tanhf_(a2);
            const float og = sigmf(a3);
            const float cn = fmaf(fg, cb[u * SMP], ig * gv);
            cb[u * SMP] = cn;
            hbw[u * SMP] = og * tanhf_(cn);
        }

        __syncthreads();               // h_new complete
#define RELOAD(i) h##i = hrd[(i) * SMP];
        RPT(RELOAD)
#undef RELOAD
        __syncthreads();               // reads done before next overwrite

        xt = xnext;
    }

    // FC head: wave 0 only (it has the full h vector too)
    if (wv == 0) {
        float l0 = b_fc[0], l1 = b_fc[1], l2 = b_fc[2], l3 = b_fc[3];
#define FCK(k) \
        l0 = fmaf(h##k, W_fc[k],       l0); \
        l1 = fmaf(h##k, W_fc[40 + k],  l1); \
        l2 = fmaf(h##k, W_fc[80 + k],  l2); \
        l3 = fmaf(h##k, W_fc[120 + k], l3);
        RPT(FCK)
#undef FCK

        *reinterpret_cast<float4*>(out + (long)b * C_) = make_float4(l0, l1, l2, l3);

        int am = 0;
        float best = l0;
        if (l1 > best) { best = l1; am = 1; }
        if (l2 > best) { best = l2; am = 2; }
        if (l3 > best) { best = l3; am = 3; }
        out[(long)B_ * C_ + b] = (float)am;
    }
}

extern "C" void kernel_launch(void* const* d_in, const int* in_sizes, int n_in,
                              void* d_out, int out_size, void* d_ws, size_t ws_size,
                              hipStream_t stream) {
    const float* x    = (const float*)d_in[0];
    const float* W_ih = (const float*)d_in[1];
    const float* W_hh = (const float*)d_in[2];
    const float* b_ih = (const float*)d_in[3];
    const float* b_hh = (const float*)d_in[4];
    const float* W_fc = (const float*)d_in[5];
    const float* b_fc = (const float*)d_in[6];
    float* out = (float*)d_out;

    dim3 block(BLK);
    dim3 grid(B_ / SMP);
    hipLaunchKernelGGL(lstm_fused_kernel, grid, block, 0, stream,
                       x, W_ih, W_hh, b_ih, b_hh, W_fc, b_fc, out);
}

// Round 5
// 1395.152 us; speedup vs baseline: 2.7931x; 2.7931x over previous
//
#include <hip/hip_runtime.h>

// B=131072 indep LSTMs, T=40, H=40, in-dim 1, FC C=4 + argmax.
// R5: R4's 2-wave split regressed because jbase=(tid>>6)*20 was not provably
// wave-uniform -> weight loads fell off the scalar pipe onto VMEM (VALUBusy
// 71->30%). Single fix vs R4: readfirstlane(jbase) forces j into an SGPR so
// W_hh rows are s_load again. Keep 4 waves/SIMD (128thr x 2048 blocks, 20KB).

#define B_ 131072
#define T_ 40
#define H_ 40
#define C_ 4
#define BLK 128          // 2 waves
#define SMP 64           // samples per block
#define JPW 20           // units per wave

__device__ __forceinline__ float fexp2f(float v) { return __builtin_amdgcn_exp2f(v); }
__device__ __forceinline__ float frcpf(float v)  { return __builtin_amdgcn_rcpf(v); }

// sigmoid(x) = 1/(1+2^(-x*log2 e)); exact tails 0/1
__device__ __forceinline__ float sigmf(float v) {
    return frcpf(1.0f + fexp2f(-1.44269504088896340736f * v));
}
// tanh(x) = 1 - 2/(1+2^(2x*log2 e)); exact tails +/-1
__device__ __forceinline__ float tanhf_(float v) {
    return 1.0f - 2.0f * frcpf(1.0f + fexp2f(2.88539008177792681472f * v));
}

#define RPT(M) M(0) M(1) M(2) M(3) M(4) M(5) M(6) M(7) M(8) M(9) \
               M(10) M(11) M(12) M(13) M(14) M(15) M(16) M(17) M(18) M(19) \
               M(20) M(21) M(22) M(23) M(24) M(25) M(26) M(27) M(28) M(29) \
               M(30) M(31) M(32) M(33) M(34) M(35) M(36) M(37) M(38) M(39)

__global__ __launch_bounds__(BLK, 4)
void lstm_fused_kernel(const float* __restrict__ x,
                       const float* __restrict__ W_ih,   // (160,1)
                       const float* __restrict__ W_hh,   // (160,40) row-major
                       const float* __restrict__ b_ih,   // (160,)
                       const float* __restrict__ b_hh,   // (160,)
                       const float* __restrict__ W_fc,   // (4,40) row-major
                       const float* __restrict__ b_fc,   // (4,)
                       float* __restrict__ out)          // [B*4 logits][B argmax-as-float]
{
    __shared__ float cbuf[H_ * SMP];   // c[j]     at [j*64 + s]
    __shared__ float hbuf[H_ * SMP];   // h_new[j] at [j*64 + s]

    const int tid = threadIdx.x;
    const int s   = tid & 63;          // sample within block
    // wave id — FORCED wave-uniform so j stays scalar (s_load weight path)
    const int wv    = __builtin_amdgcn_readfirstlane(tid >> 6);
    const int jbase = wv * JPW;
    const int b = blockIdx.x * SMP + s;
    const float* xr = x + (long)b * T_;

    float* cb  = cbuf + jbase * SMP + s;   // cb[u*SMP],  u in [0,20)
    float* hbw = hbuf + jbase * SMP + s;   // write slice
    float* hrd = hbuf + s;                 // read slice, hrd[j*SMP]

    // full hidden state in named regs (both waves keep all 40)
#define DECLH(i) float h##i = 0.0f;
    RPT(DECLH)
#undef DECLH

    // zero own cell-state slice
#pragma unroll
    for (int u = 0; u < JPW; ++u) cb[u * SMP] = 0.0f;

    float xt = xr[0];

#pragma unroll 1
    for (int t = 0; t < T_; ++t) {
        const int tn = (t + 1 < T_) ? (t + 1) : (T_ - 1);
        const float xnext = xr[tn];    // prefetch next scalar input

#pragma unroll 1
        for (int u = 0; u < JPW; ++u) {
            const int j = __builtin_amdgcn_readfirstlane(jbase + u); // scalar j
            const float* W0 = W_hh + j * H_;
            const float* W1 = W0 + 40 * H_;
            const float* W2 = W0 + 80 * H_;
            const float* W3 = W0 + 120 * H_;
            float a0 = fmaf(xt, W_ih[j],       b_ih[j]       + b_hh[j]);
            float a1 = fmaf(xt, W_ih[40 + j],  b_ih[40 + j]  + b_hh[40 + j]);
            float a2 = fmaf(xt, W_ih[80 + j],  b_ih[80 + j]  + b_hh[80 + j]);
            float a3 = fmaf(xt, W_ih[120 + j], b_ih[120 + j] + b_hh[120 + j]);
#define MACK(k) \
            a0 = fmaf(h##k, W0[k], a0); \
            a1 = fmaf(h##k, W1[k], a1); \
            a2 = fmaf(h##k, W2[k], a2); \
            a3 = fmaf(h##k, W3[k], a3);
            RPT(MACK)
#undef MACK
            const float ig = sigmf(a0);
            const float fg = sigmf(a1);
            const float gv = tanhf_(a2);
            const float og = sigmf(a3);
            const float cn = fmaf(fg, cb[u * SMP], ig * gv);
            cb[u * SMP] = cn;
            hbw[u * SMP] = og * tanhf_(cn);
        }

        __syncthreads();               // h_new complete
#define RELOAD(i) h##i = hrd[(i) * SMP];
        RPT(RELOAD)
#undef RELOAD
        __syncthreads();               // reads done before next overwrite

        xt = xnext;
    }

    // FC head: wave 0 only (holds the full h vector)
    if (wv == 0) {
        float l0 = b_fc[0], l1 = b_fc[1], l2 = b_fc[2], l3 = b_fc[3];
#define FCK(k) \
        l0 = fmaf(h##k, W_fc[k],       l0); \
        l1 = fmaf(h##k, W_fc[40 + k],  l1); \
        l2 = fmaf(h##k, W_fc[80 + k],  l2); \
        l3 = fmaf(h##k, W_fc[120 + k], l3);
        RPT(FCK)
#undef FCK

        *reinterpret_cast<float4*>(out + (long)b * C_) = make_float4(l0, l1, l2, l3);

        int am = 0;
        float best = l0;
        if (l1 > best) { best = l1; am = 1; }
        if (l2 > best) { best = l2; am = 2; }
        if (l3 > best) { best = l3; am = 3; }
        out[(long)B_ * C_ + b] = (float)am;
    }
}

extern "C" void kernel_launch(void* const* d_in, const int* in_sizes, int n_in,
                              void* d_out, int out_size, void* d_ws, size_t ws_size,
                              hipStream_t stream) {
    const float* x    = (const float*)d_in[0];
    const float* W_ih = (const float*)d_in[1];
    const float* W_hh = (const float*)d_in[2];
    const float* b_ih = (const float*)d_in[3];
    const float* b_hh = (const float*)d_in[4];
    const float* W_fc = (const float*)d_in[5];
    const float* b_fc = (const float*)d_in[6];
    float* out = (float*)d_out;

    dim3 block(BLK);
    dim3 grid(B_ / SMP);
    hipLaunchKernelGGL(lstm_fused_kernel, grid, block, 0, stream,
                       x, W_ih, W_hh, b_ih, b_hh, W_fc, b_fc, out);
}

// Round 6
// 485.256 us; speedup vs baseline: 8.0305x; 2.8751x over previous
//
#include <hip/hip_runtime.h>

// B=131072 indep LSTMs, T=40, H=40, in-dim 1, FC C=4 + argmax.
// R6: MFMA formulation. R5 (pure VALU + scalar weights) = 1395us, VALUBusy 81%,
// MfmaUtil 0 — vector-pipe ceiling. Here: per-step G = h_aug @ W' on the matrix
// pipe via mfma_f32_16x16x16f16 with fp16 hi/lo split (3-product Markidis =>
// ~2^-22 relative error, fp32-grade so argmax matches).
//  - wave owns 16 samples; NO inter-wave traffic, NO barriers.
//  - h_aug = [h(40), x_t, 1.0, 0pad] (K=48): input term AND bias fold into MFMA.
//  - gate columns padded 40->48 per type (192 total, 12 tiles): tiles are
//    type-homogeneous; i/f/g/o of unit j share (lane, reg) across tiles.
//  - W' pre-scaled by -log2e (i,f,o) / +2log2e (g): activation needs no mul.
//  - W' split fp16 hi/lo ONCE in prologue, held in regs (12 tiles x 3 K-sub x
//    hi/lo = 144 VGPRs).
//  - h relayout C->A via per-wave LDS (16 rows x stride 68 floats: 2-way bank
//    alias only = free; 68*4 waves = 17408 B).

#define B_    131072
#define T_    40
#define H_    40
#define C_    4
#define BLK   256
#define WPB   4
#define SPW   16          // samples per wave
#define SPB   64          // samples per block
#define LROW  68          // padded LDS row stride (floats); 68%32=4 -> 2-way only
#define NT    12          // 192 padded gate columns / 16
#define LOG2E 1.44269504088896340736f

typedef _Float16 half4v __attribute__((ext_vector_type(4)));
typedef float    f32x4  __attribute__((ext_vector_type(4)));

__device__ __forceinline__ float fexp2f(float v){ return __builtin_amdgcn_exp2f(v); }
__device__ __forceinline__ float frcpf (float v){ return __builtin_amdgcn_rcpf(v); }

__global__ __launch_bounds__(BLK, 2)
void lstm_mfma_kernel(const float* __restrict__ x,
                      const float* __restrict__ W_ih,   // (160,1)
                      const float* __restrict__ W_hh,   // (160,40) row-major
                      const float* __restrict__ b_ih,   // (160,)
                      const float* __restrict__ b_hh,   // (160,)
                      const float* __restrict__ W_fc,   // (4,40) row-major
                      const float* __restrict__ b_fc,   // (4,)
                      float* __restrict__ out)          // [B*4 logits][B argmax]
{
    __shared__ float lds[WPB * SPW * LROW];

    const int tid  = threadIdx.x;
    const int wv   = __builtin_amdgcn_readfirstlane(tid >> 6);
    const int lane = tid & 63;
    const int col  = lane & 15;        // MFMA n / m index
    const int quad = lane >> 4;        // MFMA k-group / C-row group
    const int sbase = blockIdx.x * SPB + wv * SPW;

    float* hbase = lds + wv * (SPW * LROW);

    // ---------------- prologue: zero LDS slice, bias-one column ----------------
#pragma unroll
    for (int i = 0; i < (SPW * LROW) / 64; ++i)     // 1088/64 = 17
        hbase[i * 64 + lane] = 0.0f;
    if (quad == 0) hbase[col * LROW + 41] = 1.0f;   // h_aug[m][41] = 1.0 (bias row)

    // ---------------- prologue: load + scale + fp16-split B fragments ----------
    // B[k][n]: lane holds k = 16*s + 4*quad + j (j=0..3), n = col (within tile).
    half4v Bh[NT][3], Bl[NT][3];
#pragma unroll
    for (int tau = 0; tau < NT; ++tau) {
        const int   tt    = tau / 3;                 // gate type 0:i 1:f 2:g 3:o
        const int   ubase = (tau % 3) * 16;
        const float scale = (tt == 2) ? (2.0f * LOG2E) : (-LOG2E);
        const int   u     = ubase + col;             // unit index (0..47)
        const bool  valid = (u < H_);
        const int   r     = tt * H_ + (valid ? u : (H_ - 1));  // gate row, clamped
#pragma unroll
        for (int s = 0; s < 3; ++s) {
            float4 wv4;
            if (s < 2) {
                wv4 = *reinterpret_cast<const float4*>(W_hh + r * H_ + 16 * s + 4 * quad);
            } else {
                if (quad == 0)      wv4 = *reinterpret_cast<const float4*>(W_hh + r * H_ + 32);
                else if (quad == 1) wv4 = *reinterpret_cast<const float4*>(W_hh + r * H_ + 36);
                else if (quad == 2) wv4 = make_float4(W_ih[r], b_ih[r] + b_hh[r], 0.0f, 0.0f);
                else                wv4 = make_float4(0.0f, 0.0f, 0.0f, 0.0f);
            }
            float wa[4] = {wv4.x, wv4.y, wv4.z, wv4.w};
            half4v bh, bl;
#pragma unroll
            for (int j = 0; j < 4; ++j) {
                float w = valid ? (wa[j] * scale) : 0.0f;
                _Float16 hi = (_Float16)w;
                bh[j] = hi;
                bl[j] = (_Float16)(w - (float)hi);
            }
            Bh[tau][s] = bh;
            Bl[tau][s] = bl;
        }
    }

    // cell state (C-layout): value (m = 4*quad + r, unit = jt*16 + col)
    f32x4 cst[3];
#pragma unroll
    for (int jt = 0; jt < 3; ++jt) cst[jt] = (f32x4){0.f, 0.f, 0.f, 0.f};

    const f32x4 zc = (f32x4){0.f, 0.f, 0.f, 0.f};

    // x prefetch for t=0 (per-lane sample m = col; 2.5KB working set, L1-hot)
    const float* xrow = x + (long)(sbase + col) * T_;
    float xv = xrow[0];

    // ---------------- recurrence ----------------
#pragma unroll 1
    for (int t = 0; t < T_; ++t) {
        // stage x_t into h_aug col 40 (quad-0 lanes cover all 16 rows)
        if (quad == 0) hbase[col * LROW + 40] = xv;
        const int tn = (t + 1 < T_) ? (t + 1) : (T_ - 1);
        const float xnext = xrow[tn];

        // A fragments: lane needs h_aug[m = col][k = 16*s + 4*quad + j]
        half4v ah[3], al[3];
        {
            const float* myrow = hbase + col * LROW;
#pragma unroll
            for (int s = 0; s < 3; ++s) {
                f32x4 hv = *reinterpret_cast<const f32x4*>(myrow + 16 * s + 4 * quad);
                half4v h_, l_;
#pragma unroll
                for (int j = 0; j < 4; ++j) {
                    _Float16 hi = (_Float16)hv[j];
                    h_[j] = hi;
                    l_[j] = (_Float16)(hv[j] - (float)hi);
                }
                ah[s] = h_; al[s] = l_;
            }
        }

        // MFMA: 12 tiles x 3 K-subtiles x 3 split-products
        f32x4 acc[NT];
#pragma unroll
        for (int tau = 0; tau < NT; ++tau) {
            f32x4 a = __builtin_amdgcn_mfma_f32_16x16x16f16(ah[0], Bh[tau][0], zc, 0, 0, 0);
            a = __builtin_amdgcn_mfma_f32_16x16x16f16(al[0], Bh[tau][0], a, 0, 0, 0);
            a = __builtin_amdgcn_mfma_f32_16x16x16f16(ah[0], Bl[tau][0], a, 0, 0, 0);
#pragma unroll
            for (int s = 1; s < 3; ++s) {
                a = __builtin_amdgcn_mfma_f32_16x16x16f16(ah[s], Bh[tau][s], a, 0, 0, 0);
                a = __builtin_amdgcn_mfma_f32_16x16x16f16(al[s], Bh[tau][s], a, 0, 0, 0);
                a = __builtin_amdgcn_mfma_f32_16x16x16f16(ah[s], Bl[tau][s], a, 0, 0, 0);
            }
            acc[tau] = a;
        }

        // activations in C-layout, in place. Pre-scaled inputs:
        //   i,f,o tiles: sigmoid = rcp(1 + exp2(y))
        //   g tiles:     tanh    = 1 - 2*rcp(1 + exp2(y))
#pragma unroll
        for (int tau = 0; tau < NT; ++tau) {
#pragma unroll
            for (int r = 0; r < 4; ++r) {
                float e  = fexp2f(acc[tau][r]);
                float rr = frcpf(1.0f + e);
                acc[tau][r] = (tau / 3 == 2) ? fmaf(-2.0f, rr, 1.0f) : rr;
            }
        }

        // combine + write h_new back to LDS (A-layout rows)
#pragma unroll
        for (int jt = 0; jt < 3; ++jt) {
#pragma unroll
            for (int r = 0; r < 4; ++r) {
                float ig = acc[jt][r];
                float fg = acc[3 + jt][r];
                float gv = acc[6 + jt][r];
                float og = acc[9 + jt][r];
                float cn = fmaf(fg, cst[jt][r], ig * gv);
                cst[jt][r] = cn;
                float e  = fexp2f(cn * (2.0f * LOG2E));
                float rr = frcpf(1.0f + e);
                float th = fmaf(-2.0f, rr, 1.0f);
                float hn = og * th;
                int u = jt * 16 + col;
                int dst = (jt < 2) ? u : ((col < 8) ? u : u + 8);  // pad -> dump 48..55
                hbase[(4 * quad + r) * LROW + dst] = hn;
            }
        }

        xv = xnext;
    }

    // ---------------- epilogue: FC + argmax ----------------
    // lane (m = col, cc = quad): logit[m][cc]
    {
        const float* myrow = hbase + col * LROW;
        float acc = b_fc[quad];
#pragma unroll
        for (int jj = 0; jj < 10; ++jj) {
            f32x4 hv = *reinterpret_cast<const f32x4*>(myrow + 4 * jj);
            float4 wv4 = *reinterpret_cast<const float4*>(W_fc + quad * H_ + 4 * jj);
            acc = fmaf(hv[0], wv4.x, acc);
            acc = fmaf(hv[1], wv4.y, acc);
            acc = fmaf(hv[2], wv4.z, acc);
            acc = fmaf(hv[3], wv4.w, acc);
        }
        // logits out (coalesces within 256B segments)
        out[(long)(sbase + col) * C_ + quad] = acc;
        // scratch for argmax at cols 56..59 of own row
        hbase[col * LROW + 56 + quad] = acc;
    }
    if (quad == 0) {
        f32x4 lg = *reinterpret_cast<const f32x4*>(hbase + col * LROW + 56);
        int am = 0;
        float best = lg[0];
        if (lg[1] > best) { best = lg[1]; am = 1; }
        if (lg[2] > best) { best = lg[2]; am = 2; }
        if (lg[3] > best) { best = lg[3]; am = 3; }
        out[(long)B_ * C_ + sbase + col] = (float)am;
    }
}

extern "C" void kernel_launch(void* const* d_in, const int* in_sizes, int n_in,
                              void* d_out, int out_size, void* d_ws, size_t ws_size,
                              hipStream_t stream) {
    const float* x    = (const float*)d_in[0];
    const float* W_ih = (const float*)d_in[1];
    const float* W_hh = (const float*)d_in[2];
    const float* b_ih = (const float*)d_in[3];
    const float* b_hh = (const float*)d_in[4];
    const float* W_fc = (const float*)d_in[5];
    const float* b_fc = (const float*)d_in[6];
    float* out = (float*)d_out;

    dim3 block(BLK);
    dim3 grid(B_ / SPB);
    hipLaunchKernelGGL(lstm_mfma_kernel, grid, block, 0, stream,
                       x, W_ih, W_hh, b_ih, b_hh, W_fc, b_fc, out);
}

// Round 7
// 429.810 us; speedup vs baseline: 9.0665x; 1.1290x over previous
//
#include <hip/hip_runtime.h>

// B=131072 indep LSTMs, T=40, H=40, in-dim 1, FC C=4 + argmax.
// R7 (from R6 @ 485us, MfmaUtil 53 / VALUBusy 64, 2 blocks/CU):
//  1) K=48 split as one 16x16x32_f16 + one 16x16x16f16 per (tile,product):
//     108 -> 72 MFMAs/step (-33% matrix pipe + issue slots). Same data/numerics.
//  2) Step phased by unit-group jt (tiles {jt,3+jt,6+jt,9+jt}): live acc
//     48 -> 16 AGPRs; phase p+1 MFMA (dep only on step-start A-frags) can
//     overlap phase p activations within the wave.
// Layout/numerics identical to R6 otherwise: h_aug=[h(40),x,1,pad] K=48,
// gate types padded 40->48 (12 tiles, type-homogeneous), W' pre-scaled by
// -log2e (i,f,o) / +2log2e (g), fp16 hi/lo 3-product (error < harness floor).

#define B_    131072
#define T_    40
#define H_    40
#define C_    4
#define BLK   256
#define WPB   4
#define SPW   16          // samples per wave
#define SPB   64          // samples per block
#define LROW  68          // padded LDS row stride (floats); 68%32=4 -> 2-way only
#define NT    12          // 192 padded gate columns / 16
#define LOG2E 1.44269504088896340736f

typedef _Float16 half4v __attribute__((ext_vector_type(4)));
typedef _Float16 half8v __attribute__((ext_vector_type(8)));
typedef float    f32x4  __attribute__((ext_vector_type(4)));

__device__ __forceinline__ float fexp2f(float v){ return __builtin_amdgcn_exp2f(v); }
__device__ __forceinline__ float frcpf (float v){ return __builtin_amdgcn_rcpf(v); }

__global__ __launch_bounds__(BLK, 2)
void lstm_mfma_kernel(const float* __restrict__ x,
                      const float* __restrict__ W_ih,   // (160,1)
                      const float* __restrict__ W_hh,   // (160,40) row-major
                      const float* __restrict__ b_ih,   // (160,)
                      const float* __restrict__ b_hh,   // (160,)
                      const float* __restrict__ W_fc,   // (4,40) row-major
                      const float* __restrict__ b_fc,   // (4,)
                      float* __restrict__ out)          // [B*4 logits][B argmax]
{
    __shared__ float lds[WPB * SPW * LROW];

    const int tid  = threadIdx.x;
    const int wv   = __builtin_amdgcn_readfirstlane(tid >> 6);
    const int lane = tid & 63;
    const int col  = lane & 15;        // MFMA m / n index
    const int quad = lane >> 4;        // MFMA k-group / C-row group
    const int sbase = blockIdx.x * SPB + wv * SPW;

    float* hbase = lds + wv * (SPW * LROW);

    // ---------------- prologue: zero LDS slice, bias-one column ----------------
#pragma unroll
    for (int i = 0; i < (SPW * LROW) / 64; ++i)     // 1088/64 = 17
        hbase[i * 64 + lane] = 0.0f;
    if (quad == 0) hbase[col * LROW + 41] = 1.0f;   // h_aug[m][41] = 1.0 (bias)

    // ---------------- prologue: load + scale + fp16-split B fragments ----------
    // K32 frag: lane holds k = 8*quad + j (j=0..7), n = col.
    // K16 frag: lane holds k = 32 + 4*quad + j (j=0..3), n = col.
    half8v Bh32[NT], Bl32[NT];
    half4v Bh16[NT], Bl16[NT];
#pragma unroll
    for (int tau = 0; tau < NT; ++tau) {
        const int   tt    = tau / 3;                 // gate type 0:i 1:f 2:g 3:o
        const int   ubase = (tau % 3) * 16;
        const float scale = (tt == 2) ? (2.0f * LOG2E) : (-LOG2E);
        const int   u     = ubase + col;             // padded unit index (0..47)
        const bool  valid = (u < H_);
        const int   r     = tt * H_ + (valid ? u : (H_ - 1));  // clamped row

        // K32 part: 8 consecutive floats of row r at 8*quad
        {
            float4 w0 = *reinterpret_cast<const float4*>(W_hh + r * H_ + 8 * quad);
            float4 w1 = *reinterpret_cast<const float4*>(W_hh + r * H_ + 8 * quad + 4);
            float wa[8] = {w0.x, w0.y, w0.z, w0.w, w1.x, w1.y, w1.z, w1.w};
            half8v bh, bl;
#pragma unroll
            for (int j = 0; j < 8; ++j) {
                float w = valid ? (wa[j] * scale) : 0.0f;
                _Float16 hi = (_Float16)w;
                bh[j] = hi;
                bl[j] = (_Float16)(w - (float)hi);
            }
            Bh32[tau] = bh; Bl32[tau] = bl;
        }
        // K16 part: k = 32+4*quad+j
        {
            float4 wv4;
            if (quad == 0)      wv4 = *reinterpret_cast<const float4*>(W_hh + r * H_ + 32);
            else if (quad == 1) wv4 = *reinterpret_cast<const float4*>(W_hh + r * H_ + 36);
            else if (quad == 2) wv4 = make_float4(W_ih[r], b_ih[r] + b_hh[r], 0.0f, 0.0f);
            else                wv4 = make_float4(0.0f, 0.0f, 0.0f, 0.0f);
            float wa[4] = {wv4.x, wv4.y, wv4.z, wv4.w};
            half4v bh, bl;
#pragma unroll
            for (int j = 0; j < 4; ++j) {
                float w = valid ? (wa[j] * scale) : 0.0f;
                _Float16 hi = (_Float16)w;
                bh[j] = hi;
                bl[j] = (_Float16)(w - (float)hi);
            }
            Bh16[tau] = bh; Bl16[tau] = bl;
        }
    }

    // cell state (C-layout): lane value (m = 4*quad + r, unit = jt*16 + col)
    f32x4 cst[3];
#pragma unroll
    for (int jt = 0; jt < 3; ++jt) cst[jt] = (f32x4){0.f, 0.f, 0.f, 0.f};

    const f32x4 zc = (f32x4){0.f, 0.f, 0.f, 0.f};

    const float* xrow = x + (long)(sbase + col) * T_;
    float xv = xrow[0];

    // ---------------- recurrence ----------------
#pragma unroll 1
    for (int t = 0; t < T_; ++t) {
        if (quad == 0) hbase[col * LROW + 40] = xv;   // stage x_t (k=40)
        const int tn = (t + 1 < T_) ? (t + 1) : (T_ - 1);
        const float xnext = xrow[tn];

        // A fragments for the whole step (phases reuse them)
        half8v ah32, al32; half4v ah16, al16;
        {
            const float* myrow = hbase + col * LROW;
            f32x4 hv0 = *reinterpret_cast<const f32x4*>(myrow + 8 * quad);
            f32x4 hv1 = *reinterpret_cast<const f32x4*>(myrow + 8 * quad + 4);
            f32x4 hv2 = *reinterpret_cast<const f32x4*>(myrow + 32 + 4 * quad);
#pragma unroll
            for (int j = 0; j < 4; ++j) {
                _Float16 hi0 = (_Float16)hv0[j];
                ah32[j] = hi0; al32[j] = (_Float16)(hv0[j] - (float)hi0);
                _Float16 hi1 = (_Float16)hv1[j];
                ah32[4 + j] = hi1; al32[4 + j] = (_Float16)(hv1[j] - (float)hi1);
                _Float16 hi2 = (_Float16)hv2[j];
                ah16[j] = hi2; al16[j] = (_Float16)(hv2[j] - (float)hi2);
            }
        }

        // 3 phases of unit-groups; per phase 4 tiles (i,f,g,o), 6 MFMAs each
#pragma unroll
        for (int jt = 0; jt < 3; ++jt) {
#define DOT48(tau, dst)                                                          \
            {                                                                    \
                f32x4 a = __builtin_amdgcn_mfma_f32_16x16x32_f16(ah32, Bh32[tau], zc, 0, 0, 0); \
                a = __builtin_amdgcn_mfma_f32_16x16x32_f16(al32, Bh32[tau], a, 0, 0, 0); \
                a = __builtin_amdgcn_mfma_f32_16x16x32_f16(ah32, Bl32[tau], a, 0, 0, 0); \
                a = __builtin_amdgcn_mfma_f32_16x16x16f16(ah16, Bh16[tau], a, 0, 0, 0); \
                a = __builtin_amdgcn_mfma_f32_16x16x16f16(al16, Bh16[tau], a, 0, 0, 0); \
                a = __builtin_amdgcn_mfma_f32_16x16x16f16(ah16, Bl16[tau], a, 0, 0, 0); \
                dst = a;                                                         \
            }
            f32x4 ai, af, ag, ao;
            DOT48(jt, ai)
            DOT48(3 + jt, af)
            DOT48(6 + jt, ag)
            DOT48(9 + jt, ao)
#undef DOT48

#pragma unroll
            for (int r = 0; r < 4; ++r) {
                // pre-scaled inputs: sigmoid = rcp(1+exp2(y)); tanh = 1-2*rcp(1+exp2(y))
                float ig = frcpf(1.0f + fexp2f(ai[r]));
                float fg = frcpf(1.0f + fexp2f(af[r]));
                float gv = fmaf(-2.0f, frcpf(1.0f + fexp2f(ag[r])), 1.0f);
                float og = frcpf(1.0f + fexp2f(ao[r]));
                float cn = fmaf(fg, cst[jt][r], ig * gv);
                cst[jt][r] = cn;
                float th = fmaf(-2.0f, frcpf(1.0f + fexp2f(cn * (2.0f * LOG2E))), 1.0f);
                float hn = og * th;
                int u = jt * 16 + col;
                int dst = (jt < 2) ? u : ((col < 8) ? u : u + 8);  // pad -> 48..55
                hbase[(4 * quad + r) * LROW + dst] = hn;
            }
        }

        xv = xnext;
    }

    // ---------------- epilogue: FC + argmax ----------------
    {
        const float* myrow = hbase + col * LROW;
        float acc = b_fc[quad];
#pragma unroll
        for (int jj = 0; jj < 10; ++jj) {
            f32x4 hv = *reinterpret_cast<const f32x4*>(myrow + 4 * jj);
            float4 wv4 = *reinterpret_cast<const float4*>(W_fc + quad * H_ + 4 * jj);
            acc = fmaf(hv[0], wv4.x, acc);
            acc = fmaf(hv[1], wv4.y, acc);
            acc = fmaf(hv[2], wv4.z, acc);
            acc = fmaf(hv[3], wv4.w, acc);
        }
        out[(long)(sbase + col) * C_ + quad] = acc;
        hbase[col * LROW + 56 + quad] = acc;   // scratch for argmax
    }
    if (quad == 0) {
        f32x4 lg = *reinterpret_cast<const f32x4*>(hbase + col * LROW + 56);
        int am = 0;
        float best = lg[0];
        if (lg[1] > best) { best = lg[1]; am = 1; }
        if (lg[2] > best) { best = lg[2]; am = 2; }
        if (lg[3] > best) { best = lg[3]; am = 3; }
        out[(long)B_ * C_ + sbase + col] = (float)am;
    }
}

extern "C" void kernel_launch(void* const* d_in, const int* in_sizes, int n_in,
                              void* d_out, int out_size, void* d_ws, size_t ws_size,
                              hipStream_t stream) {
    const float* x    = (const float*)d_in[0];
    const float* W_ih = (const float*)d_in[1];
    const float* W_hh = (const float*)d_in[2];
    const float* b_ih = (const float*)d_in[3];
    const float* b_hh = (const float*)d_in[4];
    const float* W_fc = (const float*)d_in[5];
    const float* b_fc = (const float*)d_in[6];
    float* out = (float*)d_out;

    dim3 block(BLK);
    dim3 grid(B_ / SPB);
    hipLaunchKernelGGL(lstm_mfma_kernel, grid, block, 0, stream,
                       x, W_ih, W_hh, b_ih, b_hh, W_fc, b_fc, out);
}

// Round 10
// 422.552 us; speedup vs baseline: 9.2222x; 1.0172x over previous
//
#include <hip/hip_runtime.h>

// B=131072 indep LSTMs, T=40, H=40, in-dim 1, FC C=4 + argmax.
// R10 = R7 (exact 3-product, passing @430us) + algebraic transcendental
// reduction. R8 (Bl via LDS) corrupted data; R9 (fp16 B) flipped argmax —
// argmax requires fp32-grade logits, so precision stays R7-exact.
// R7 measurement: trans unit is the bottleneck (120 trans x 16cyc = 1920 of
// 2288 cyc/wave-step). Here: merge rcps via common denominators:
//   cn = [c(1+e_i)(1+E_g) + (E_g-1)(1+e_f)] / [(1+e_i)(1+E_g)(1+e_f)]  (3->1 rcp)
//   hn = (E_c-1) / [(1+e_o)(1+E_c)]                                    (2->1 rcp)
// 10 -> 7 trans/element (5 exp2 + 2 rcp); trans/wave-step 1920 -> 1344 cyc.
// W' pre-scale unchanged: -log2e (i,f,o), +2log2e (g) => e = exp2(mfma out).

#define B_    131072
#define T_    40
#define H_    40
#define C_    4
#define BLK   256
#define WPB   4
#define SPW   16          // samples per wave
#define SPB   64          // samples per block
#define LROW  68          // padded LDS row stride (floats); 68%32=4 -> 2-way only
#define NT    12          // 192 padded gate columns / 16
#define LOG2E 1.44269504088896340736f

typedef _Float16 half4v __attribute__((ext_vector_type(4)));
typedef _Float16 half8v __attribute__((ext_vector_type(8)));
typedef float    f32x4  __attribute__((ext_vector_type(4)));

__device__ __forceinline__ float fexp2f(float v){ return __builtin_amdgcn_exp2f(v); }
__device__ __forceinline__ float frcpf (float v){ return __builtin_amdgcn_rcpf(v); }

__global__ __launch_bounds__(BLK, 2)
void lstm_mfma_kernel(const float* __restrict__ x,
                      const float* __restrict__ W_ih,   // (160,1)
                      const float* __restrict__ W_hh,   // (160,40) row-major
                      const float* __restrict__ b_ih,   // (160,)
                      const float* __restrict__ b_hh,   // (160,)
                      const float* __restrict__ W_fc,   // (4,40) row-major
                      const float* __restrict__ b_fc,   // (4,)
                      float* __restrict__ out)          // [B*4 logits][B argmax]
{
    __shared__ float lds[WPB * SPW * LROW];

    const int tid  = threadIdx.x;
    const int wv   = __builtin_amdgcn_readfirstlane(tid >> 6);
    const int lane = tid & 63;
    const int col  = lane & 15;        // MFMA m / n index
    const int quad = lane >> 4;        // MFMA k-group / C-row group
    const int sbase = blockIdx.x * SPB + wv * SPW;

    float* hbase = lds + wv * (SPW * LROW);

    // ---------------- prologue: zero LDS slice, bias-one column ----------------
#pragma unroll
    for (int i = 0; i < (SPW * LROW) / 64; ++i)     // 1088/64 = 17
        hbase[i * 64 + lane] = 0.0f;
    if (quad == 0) hbase[col * LROW + 41] = 1.0f;   // h_aug[m][41] = 1.0 (bias)

    // ---------------- prologue: load + scale + fp16-split B fragments ----------
    // K32 frag: lane holds k = 8*quad + j (j=0..7), n = col.
    // K16 frag: lane holds k = 32 + 4*quad + j (j=0..3), n = col.
    half8v Bh32[NT], Bl32[NT];
    half4v Bh16[NT], Bl16[NT];
#pragma unroll
    for (int tau = 0; tau < NT; ++tau) {
        const int   tt    = tau / 3;                 // gate type 0:i 1:f 2:g 3:o
        const int   ubase = (tau % 3) * 16;
        const float scale = (tt == 2) ? (2.0f * LOG2E) : (-LOG2E);
        const int   u     = ubase + col;             // padded unit index (0..47)
        const bool  valid = (u < H_);
        const int   r     = tt * H_ + (valid ? u : (H_ - 1));  // clamped row

        // K32 part: 8 consecutive floats of row r at 8*quad
        {
            float4 w0 = *reinterpret_cast<const float4*>(W_hh + r * H_ + 8 * quad);
            float4 w1 = *reinterpret_cast<const float4*>(W_hh + r * H_ + 8 * quad + 4);
            float wa[8] = {w0.x, w0.y, w0.z, w0.w, w1.x, w1.y, w1.z, w1.w};
            half8v bh, bl;
#pragma unroll
            for (int j = 0; j < 8; ++j) {
                float w = valid ? (wa[j] * scale) : 0.0f;
                _Float16 hi = (_Float16)w;
                bh[j] = hi;
                bl[j] = (_Float16)(w - (float)hi);
            }
            Bh32[tau] = bh; Bl32[tau] = bl;
        }
        // K16 part: k = 32+4*quad+j
        {
            float4 wv4;
            if (quad == 0)      wv4 = *reinterpret_cast<const float4*>(W_hh + r * H_ + 32);
            else if (quad == 1) wv4 = *reinterpret_cast<const float4*>(W_hh + r * H_ + 36);
            else if (quad == 2) wv4 = make_float4(W_ih[r], b_ih[r] + b_hh[r], 0.0f, 0.0f);
            else                wv4 = make_float4(0.0f, 0.0f, 0.0f, 0.0f);
            float wa[4] = {wv4.x, wv4.y, wv4.z, wv4.w};
            half4v bh, bl;
#pragma unroll
            for (int j = 0; j < 4; ++j) {
                float w = valid ? (wa[j] * scale) : 0.0f;
                _Float16 hi = (_Float16)w;
                bh[j] = hi;
                bl[j] = (_Float16)(w - (float)hi);
            }
            Bh16[tau] = bh; Bl16[tau] = bl;
        }
    }

    // cell state (C-layout): lane value (m = 4*quad + r, unit = jt*16 + col)
    f32x4 cst[3];
#pragma unroll
    for (int jt = 0; jt < 3; ++jt) cst[jt] = (f32x4){0.f, 0.f, 0.f, 0.f};

    const f32x4 zc = (f32x4){0.f, 0.f, 0.f, 0.f};

    const float* xrow = x + (long)(sbase + col) * T_;
    float xv = xrow[0];

    // ---------------- recurrence ----------------
#pragma unroll 1
    for (int t = 0; t < T_; ++t) {
        if (quad == 0) hbase[col * LROW + 40] = xv;   // stage x_t (k=40)
        const int tn = (t + 1 < T_) ? (t + 1) : (T_ - 1);
        const float xnext = xrow[tn];

        // A fragments for the whole step (phases reuse them)
        half8v ah32, al32; half4v ah16, al16;
        {
            const float* myrow = hbase + col * LROW;
            f32x4 hv0 = *reinterpret_cast<const f32x4*>(myrow + 8 * quad);
            f32x4 hv1 = *reinterpret_cast<const f32x4*>(myrow + 8 * quad + 4);
            f32x4 hv2 = *reinterpret_cast<const f32x4*>(myrow + 32 + 4 * quad);
#pragma unroll
            for (int j = 0; j < 4; ++j) {
                _Float16 hi0 = (_Float16)hv0[j];
                ah32[j] = hi0; al32[j] = (_Float16)(hv0[j] - (float)hi0);
                _Float16 hi1 = (_Float16)hv1[j];
                ah32[4 + j] = hi1; al32[4 + j] = (_Float16)(hv1[j] - (float)hi1);
                _Float16 hi2 = (_Float16)hv2[j];
                ah16[j] = hi2; al16[j] = (_Float16)(hv2[j] - (float)hi2);
            }
        }

        // 3 phases of unit-groups; per phase 4 tiles (i,f,g,o), 6 MFMAs each
#pragma unroll
        for (int jt = 0; jt < 3; ++jt) {
#define DOT48(tau, dst)                                                          \
            {                                                                    \
                f32x4 a = __builtin_amdgcn_mfma_f32_16x16x32_f16(ah32, Bh32[tau], zc, 0, 0, 0); \
                a = __builtin_amdgcn_mfma_f32_16x16x32_f16(al32, Bh32[tau], a, 0, 0, 0); \
                a = __builtin_amdgcn_mfma_f32_16x16x32_f16(ah32, Bl32[tau], a, 0, 0, 0); \
                a = __builtin_amdgcn_mfma_f32_16x16x16f16(ah16, Bh16[tau], a, 0, 0, 0); \
                a = __builtin_amdgcn_mfma_f32_16x16x16f16(al16, Bh16[tau], a, 0, 0, 0); \
                a = __builtin_amdgcn_mfma_f32_16x16x16f16(ah16, Bl16[tau], a, 0, 0, 0); \
                dst = a;                                                         \
            }
            f32x4 ai, af, ag, ao;
            DOT48(jt, ai)
            DOT48(3 + jt, af)
            DOT48(6 + jt, ag)
            DOT48(9 + jt, ao)
#undef DOT48

#pragma unroll
            for (int r = 0; r < 4; ++r) {
                // merged-rcp activations (exact algebra):
                //   e_i=exp2(y_i) etc (W' pre-scaled so y = -a/ln2 for i,f,o;
                //   y = +2a/ln2 for g)
                //   cn = [c*(1+e_i)(1+E_g) + (E_g-1)(1+e_f)] / [(1+e_i)(1+E_g)(1+e_f)]
                //   hn = (E_c-1) / [(1+e_o)(1+E_c)],  E_c = exp2(2*log2e*cn)
                const float ei = fexp2f(ai[r]);
                const float ef = fexp2f(af[r]);
                const float Eg = fexp2f(ag[r]);
                const float eo = fexp2f(ao[r]);
                const float u_ = 1.0f + ei;
                const float v_ = 1.0f + Eg;
                const float w_ = 1.0f + ef;
                const float p_ = u_ * v_;
                const float q_ = (Eg - 1.0f) * w_;
                const float num = fmaf(cst[jt][r], p_, q_);
                const float cn  = num * frcpf(p_ * w_);
                cst[jt][r] = cn;
                const float Ec = fexp2f(cn * (2.0f * LOG2E));
                const float hn = (Ec - 1.0f) * frcpf((1.0f + eo) * (1.0f + Ec));
                int u = jt * 16 + col;
                int dst = (jt < 2) ? u : ((col < 8) ? u : u + 8);  // pad -> 48..55
                hbase[(4 * quad + r) * LROW + dst] = hn;
            }
        }

        xv = xnext;
    }

    // ---------------- epilogue: FC + argmax ----------------
    {
        const float* myrow = hbase + col * LROW;
        float acc = b_fc[quad];
#pragma unroll
        for (int jj = 0; jj < 10; ++jj) {
            f32x4 hv = *reinterpret_cast<const f32x4*>(myrow + 4 * jj);
            float4 wv4 = *reinterpret_cast<const float4*>(W_fc + quad * H_ + 4 * jj);
            acc = fmaf(hv[0], wv4.x, acc);
            acc = fmaf(hv[1], wv4.y, acc);
            acc = fmaf(hv[2], wv4.z, acc);
            acc = fmaf(hv[3], wv4.w, acc);
        }
        out[(long)(sbase + col) * C_ + quad] = acc;
        hbase[col * LROW + 56 + quad] = acc;   // scratch for argmax
    }
    if (quad == 0) {
        f32x4 lg = *reinterpret_cast<const f32x4*>(hbase + col * LROW + 56);
        int am = 0;
        float best = lg[0];
        if (lg[1] > best) { best = lg[1]; am = 1; }
        if (lg[2] > best) { best = lg[2]; am = 2; }
        if (lg[3] > best) { best = lg[3]; am = 3; }
        out[(long)B_ * C_ + sbase + col] = (float)am;
    }
}

extern "C" void kernel_launch(void* const* d_in, const int* in_sizes, int n_in,
                              void* d_out, int out_size, void* d_ws, size_t ws_size,
                              hipStream_t stream) {
    const float* x    = (const float*)d_in[0];
    const float* W_ih = (const float*)d_in[1];
    const float* W_hh = (const float*)d_in[2];
    const float* b_ih = (const float*)d_in[3];
    const float* b_hh = (const float*)d_in[4];
    const float* W_fc = (const float*)d_in[5];
    const float* b_fc = (const float*)d_in[6];
    float* out = (float*)d_out;

    dim3 block(BLK);
    dim3 grid(B_ / SPB);
    hipLaunchKernelGGL(lstm_mfma_kernel, grid, block, 0, stream,
                       x, W_ih, W_hh, b_ih, b_hh, W_fc, b_fc, out);
}

// Round 12
// 420.186 us; speedup vs baseline: 9.2741x; 1.0056x over previous
//
#include <hip/hip_runtime.h>

// B=131072 indep LSTMs, T=40, H=40, in-dim 1, FC C=4 + argmax.
// R12 = R11 with the compile fix: cvt_pkrtz returns __fp16x2; bit_cast it
// into our _Float16-based half2v (same 32-bit reg, no codegen cost).
//  - A hi/lo split via bit-mask (and 0xFFFFE000) + exact sub + cvt_pkrtz:
//    3 VALU/element, half2-based vector build (no per-element inserts).
//    RTZ split: dropped al*bl term <= 2^-22 rel — same class as R10 (passed).
//  - t-invariant LDS pointers: all 12 hn stores + A-frag reads + x staging
//    use compile-time immediate offsets (zero addr VALU in the K-loop).
// Model (R10): exp2/rcp ~full-rate on gfx950; kernel is VALU-issue bound at
// ~2228 cyc/wave-step, 71% busy, 2 waves/SIMD (260 unified regs).

#define B_    131072
#define T_    40
#define H_    40
#define C_    4
#define BLK   256
#define WPB   4
#define SPW   16          // samples per wave
#define SPB   64          // samples per block
#define LROW  68          // padded LDS row stride (floats); 68%32=4 -> 2-way only
#define NT    12          // 192 padded gate columns / 16
#define LOG2E 1.44269504088896340736f

typedef __fp16   fp16x2 __attribute__((ext_vector_type(2)));
typedef _Float16 half2v __attribute__((ext_vector_type(2)));
typedef _Float16 half4v __attribute__((ext_vector_type(4)));
typedef _Float16 half8v __attribute__((ext_vector_type(8)));
typedef float    f32x4  __attribute__((ext_vector_type(4)));

__device__ __forceinline__ float fexp2f(float v){ return __builtin_amdgcn_exp2f(v); }
__device__ __forceinline__ float frcpf (float v){ return __builtin_amdgcn_rcpf(v); }

// packed fp32x2 -> fp16x2 (RTZ), as _Float16 vector
__device__ __forceinline__ half2v pkrtz(float a, float b) {
    fp16x2 r = __builtin_amdgcn_cvt_pkrtz(a, b);
    return __builtin_bit_cast(half2v, r);
}

// exact fp32 -> (hi, lo): hi = v with low 13 mantissa bits cleared (11 sig
// bits -> exact in fp16), lo = v - hi (exact; |lo| <= 2^-11 |v|).
__device__ __forceinline__ float himask(float v) {
    return __builtin_bit_cast(float, __builtin_bit_cast(unsigned int, v) & 0xFFFFE000u);
}

__global__ __launch_bounds__(BLK, 2)
void lstm_mfma_kernel(const float* __restrict__ x,
                      const float* __restrict__ W_ih,   // (160,1)
                      const float* __restrict__ W_hh,   // (160,40) row-major
                      const float* __restrict__ b_ih,   // (160,)
                      const float* __restrict__ b_hh,   // (160,)
                      const float* __restrict__ W_fc,   // (4,40) row-major
                      const float* __restrict__ b_fc,   // (4,)
                      float* __restrict__ out)          // [B*4 logits][B argmax]
{
    __shared__ float lds[WPB * SPW * LROW];

    const int tid  = threadIdx.x;
    const int wv   = __builtin_amdgcn_readfirstlane(tid >> 6);
    const int lane = tid & 63;
    const int col  = lane & 15;        // MFMA m / n index
    const int quad = lane >> 4;        // MFMA k-group / C-row group
    const int sbase = blockIdx.x * SPB + wv * SPW;

    float* hbase = lds + wv * (SPW * LROW);

    // ---------------- prologue: zero LDS slice, bias-one column ----------------
#pragma unroll
    for (int i = 0; i < (SPW * LROW) / 64; ++i)     // 1088/64 = 17
        hbase[i * 64 + lane] = 0.0f;
    if (quad == 0) hbase[col * LROW + 41] = 1.0f;   // h_aug[m][41] = 1.0 (bias)

    // ---------------- prologue: load + scale + fp16-split B fragments ----------
    half8v Bh32[NT], Bl32[NT];
    half4v Bh16[NT], Bl16[NT];
#pragma unroll
    for (int tau = 0; tau < NT; ++tau) {
        const int   tt    = tau / 3;                 // gate type 0:i 1:f 2:g 3:o
        const int   ubase = (tau % 3) * 16;
        const float scale = (tt == 2) ? (2.0f * LOG2E) : (-LOG2E);
        const int   u     = ubase + col;             // padded unit index (0..47)
        const bool  valid = (u < H_);
        const int   r     = tt * H_ + (valid ? u : (H_ - 1));  // clamped row

        {
            float4 w0 = *reinterpret_cast<const float4*>(W_hh + r * H_ + 8 * quad);
            float4 w1 = *reinterpret_cast<const float4*>(W_hh + r * H_ + 8 * quad + 4);
            float wa[8] = {w0.x, w0.y, w0.z, w0.w, w1.x, w1.y, w1.z, w1.w};
            half8v bh, bl;
#pragma unroll
            for (int j = 0; j < 8; ++j) {
                float w = valid ? (wa[j] * scale) : 0.0f;
                _Float16 hi = (_Float16)w;
                bh[j] = hi;
                bl[j] = (_Float16)(w - (float)hi);
            }
            Bh32[tau] = bh; Bl32[tau] = bl;
        }
        {
            float4 wv4;
            if (quad == 0)      wv4 = *reinterpret_cast<const float4*>(W_hh + r * H_ + 32);
            else if (quad == 1) wv4 = *reinterpret_cast<const float4*>(W_hh + r * H_ + 36);
            else if (quad == 2) wv4 = make_float4(W_ih[r], b_ih[r] + b_hh[r], 0.0f, 0.0f);
            else                wv4 = make_float4(0.0f, 0.0f, 0.0f, 0.0f);
            float wa[4] = {wv4.x, wv4.y, wv4.z, wv4.w};
            half4v bh, bl;
#pragma unroll
            for (int j = 0; j < 4; ++j) {
                float w = valid ? (wa[j] * scale) : 0.0f;
                _Float16 hi = (_Float16)w;
                bh[j] = hi;
                bl[j] = (_Float16)(w - (float)hi);
            }
            Bh16[tau] = bh; Bl16[tau] = bl;
        }
    }

    // cell state (C-layout): lane value (m = 4*quad + r, unit = jt*16 + col)
    f32x4 cst[3];
#pragma unroll
    for (int jt = 0; jt < 3; ++jt) cst[jt] = (f32x4){0.f, 0.f, 0.f, 0.f};

    const f32x4 zc = (f32x4){0.f, 0.f, 0.f, 0.f};

    // ---------------- t-invariant LDS pointers (immediate-offset accesses) -----
    const float* myrow = hbase + col * LROW;            // A-frag row
    const float* a32p  = myrow + 8 * quad;              // K32 reads: [0..3],[4..7]
    const float* a16p  = myrow + 32 + 4 * quad;         // K16 reads: [0..3]
    float* xslot  = hbase + col * LROW + 40;            // x_t staging (quad 0)
    float* wbase  = hbase + 4 * quad * LROW + col;      // hn stores, jt=0,1
    float* wbase2 = wbase + ((col >= 8) ? 8 : 0);       // hn stores, jt=2 (pad skip)

    const float* xrow = x + (long)(sbase + col) * T_;
    float xv = xrow[0];

    // ---------------- recurrence ----------------
#pragma unroll 1
    for (int t = 0; t < T_; ++t) {
        if (quad == 0) *xslot = xv;
        const int tn = (t + 1 < T_) ? (t + 1) : (T_ - 1);
        const float xnext = xrow[tn];

        // A fragments: mask-split (hi = masked, lo = exact residual), pkrtz pack
        half8v ah32, al32; half4v ah16, al16;
        {
            f32x4 hv0 = *reinterpret_cast<const f32x4*>(a32p);
            f32x4 hv1 = *reinterpret_cast<const f32x4*>(a32p + 4);
            f32x4 hv2 = *reinterpret_cast<const f32x4*>(a16p);

            f32x4 hi0, hi1, hi2;
#pragma unroll
            for (int j = 0; j < 4; ++j) {
                hi0[j] = himask(hv0[j]);
                hi1[j] = himask(hv1[j]);
                hi2[j] = himask(hv2[j]);
            }
            half2v h00 = pkrtz(hi0[0], hi0[1]);
            half2v h01 = pkrtz(hi0[2], hi0[3]);
            half2v h10 = pkrtz(hi1[0], hi1[1]);
            half2v h11 = pkrtz(hi1[2], hi1[3]);
            half2v l00 = pkrtz(hv0[0] - hi0[0], hv0[1] - hi0[1]);
            half2v l01 = pkrtz(hv0[2] - hi0[2], hv0[3] - hi0[3]);
            half2v l10 = pkrtz(hv1[0] - hi1[0], hv1[1] - hi1[1]);
            half2v l11 = pkrtz(hv1[2] - hi1[2], hv1[3] - hi1[3]);
            half2v h20 = pkrtz(hi2[0], hi2[1]);
            half2v h21 = pkrtz(hi2[2], hi2[3]);
            half2v l20 = pkrtz(hv2[0] - hi2[0], hv2[1] - hi2[1]);
            half2v l21 = pkrtz(hv2[2] - hi2[2], hv2[3] - hi2[3]);

            half4v a0 = __builtin_shufflevector(h00, h01, 0, 1, 2, 3);
            half4v a1 = __builtin_shufflevector(h10, h11, 0, 1, 2, 3);
            ah32 = __builtin_shufflevector(a0, a1, 0, 1, 2, 3, 4, 5, 6, 7);
            half4v b0 = __builtin_shufflevector(l00, l01, 0, 1, 2, 3);
            half4v b1 = __builtin_shufflevector(l10, l11, 0, 1, 2, 3);
            al32 = __builtin_shufflevector(b0, b1, 0, 1, 2, 3, 4, 5, 6, 7);
            ah16 = __builtin_shufflevector(h20, h21, 0, 1, 2, 3);
            al16 = __builtin_shufflevector(l20, l21, 0, 1, 2, 3);
        }

        // 3 phases of unit-groups; per phase 4 tiles (i,f,g,o), 6 MFMAs each
#pragma unroll
        for (int jt = 0; jt < 3; ++jt) {
#define DOT48(tau, dst)                                                          \
            {                                                                    \
                f32x4 a = __builtin_amdgcn_mfma_f32_16x16x32_f16(ah32, Bh32[tau], zc, 0, 0, 0); \
                a = __builtin_amdgcn_mfma_f32_16x16x32_f16(al32, Bh32[tau], a, 0, 0, 0); \
                a = __builtin_amdgcn_mfma_f32_16x16x32_f16(ah32, Bl32[tau], a, 0, 0, 0); \
                a = __builtin_amdgcn_mfma_f32_16x16x16f16(ah16, Bh16[tau], a, 0, 0, 0); \
                a = __builtin_amdgcn_mfma_f32_16x16x16f16(al16, Bh16[tau], a, 0, 0, 0); \
                a = __builtin_amdgcn_mfma_f32_16x16x16f16(ah16, Bl16[tau], a, 0, 0, 0); \
                dst = a;                                                         \
            }
            f32x4 ai, af, ag, ao;
            DOT48(jt, ai)
            DOT48(3 + jt, af)
            DOT48(6 + jt, ag)
            DOT48(9 + jt, ao)
#undef DOT48

#pragma unroll
            for (int r = 0; r < 4; ++r) {
                // merged-rcp activations (exact algebra; W' pre-scaled):
                //   cn = [c(1+e_i)(1+E_g) + (E_g-1)(1+e_f)] / [(1+e_i)(1+E_g)(1+e_f)]
                //   hn = (E_c-1) / [(1+e_o)(1+E_c)]
                const float ei = fexp2f(ai[r]);
                const float ef = fexp2f(af[r]);
                const float Eg = fexp2f(ag[r]);
                const float eo = fexp2f(ao[r]);
                const float u_ = 1.0f + ei;
                const float v_ = 1.0f + Eg;
                const float w_ = 1.0f + ef;
                const float p_ = u_ * v_;
                const float q_ = (Eg - 1.0f) * w_;
                const float num = fmaf(cst[jt][r], p_, q_);
                const float cn  = num * frcpf(p_ * w_);
                cst[jt][r] = cn;
                const float Ec = fexp2f(cn * (2.0f * LOG2E));
                const float hn = (Ec - 1.0f) * frcpf((1.0f + eo) * (1.0f + Ec));
                // immediate-offset stores (jt, r compile-time after unroll)
                if (jt < 2) wbase [r * LROW + jt * 16] = hn;
                else        wbase2[r * LROW + 32]      = hn;
            }
        }

        xv = xnext;
    }

    // ---------------- epilogue: FC + argmax ----------------
    {
        float acc = b_fc[quad];
#pragma unroll
        for (int jj = 0; jj < 10; ++jj) {
            f32x4 hv = *reinterpret_cast<const f32x4*>(myrow + 4 * jj);
            float4 wv4 = *reinterpret_cast<const float4*>(W_fc + quad * H_ + 4 * jj);
            acc = fmaf(hv[0], wv4.x, acc);
            acc = fmaf(hv[1], wv4.y, acc);
            acc = fmaf(hv[2], wv4.z, acc);
            acc = fmaf(hv[3], wv4.w, acc);
        }
        out[(long)(sbase + col) * C_ + quad] = acc;
        hbase[col * LROW + 56 + quad] = acc;   // scratch for argmax
    }
    if (quad == 0) {
        f32x4 lg = *reinterpret_cast<const f32x4*>(hbase + col * LROW + 56);
        int am = 0;
        float best = lg[0];
        if (lg[1] > best) { best = lg[1]; am = 1; }
        if (lg[2] > best) { best = lg[2]; am = 2; }
        if (lg[3] > best) { best = lg[3]; am = 3; }
        out[(long)B_ * C_ + sbase + col] = (float)am;
    }
}

extern "C" void kernel_launch(void* const* d_in, const int* in_sizes, int n_in,
                              void* d_out, int out_size, void* d_ws, size_t ws_size,
                              hipStream_t stream) {
    const float* x    = (const float*)d_in[0];
    const float* W_ih = (const float*)d_in[1];
    const float* W_hh = (const float*)d_in[2];
    const float* b_ih = (const float*)d_in[3];
    const float* b_hh = (const float*)d_in[4];
    const float* W_fc = (const float*)d_in[5];
    const float* b_fc = (const float*)d_in[6];
    float* out = (float*)d_out;

    dim3 block(BLK);
    dim3 grid(B_ / SPB);
    hipLaunchKernelGGL(lstm_mfma_kernel, grid, block, 0, stream,
                       x, W_ih, W_hh, b_ih, b_hh, W_fc, b_fc, out);
}

// Round 13
// 410.490 us; speedup vs baseline: 9.4932x; 1.0236x over previous
//
#include <hip/hip_runtime.h>

// B=131072 indep LSTMs, T=40, H=40, in-dim 1, FC C=4 + argmax.
// R13 = R12 (420us, passing) + packed-FP32 activation math:
//  - r-loop processed as r-pairs in float2 ext-vectors -> v_pk_add/mul/fma_f32
//    (CDNA full-rate 2xFP32). 14 packable ops/element -> 7 packed per pair;
//    saves ~84 VALU issue slots of ~567 per wave-step (~15% of VALU).
//  - exp2/rcp remain scalar per component (no packed transcendentals).
//  - numerically IDENTICAL elementwise ops -> absmax must stay 4.882812e-4.
// Model: VALU-issue bound, 2 waves/SIMD (unified regs ~264: Bh/Bl=144 + acc),
// VALUBusy 72%, MfmaUtil 42%; R8/R9 showed occupancy can't rise without
// losing fp32-grade B (argmax needs it).

#define B_    131072
#define T_    40
#define H_    40
#define C_    4
#define BLK   256
#define WPB   4
#define SPW   16          // samples per wave
#define SPB   64          // samples per block
#define LROW  68          // padded LDS row stride (floats); 68%32=4 -> 2-way only
#define NT    12          // 192 padded gate columns / 16
#define LOG2E 1.44269504088896340736f

typedef __fp16   fp16x2 __attribute__((ext_vector_type(2)));
typedef _Float16 half2v __attribute__((ext_vector_type(2)));
typedef _Float16 half4v __attribute__((ext_vector_type(4)));
typedef _Float16 half8v __attribute__((ext_vector_type(8)));
typedef float    f32x2  __attribute__((ext_vector_type(2)));
typedef float    f32x4  __attribute__((ext_vector_type(4)));

__device__ __forceinline__ float fexp2f(float v){ return __builtin_amdgcn_exp2f(v); }
__device__ __forceinline__ float frcpf (float v){ return __builtin_amdgcn_rcpf(v); }

// component-wise exp2 / rcp on a pair (transcendentals have no packed form)
__device__ __forceinline__ f32x2 fexp2v(f32x2 v){ return (f32x2){fexp2f(v[0]), fexp2f(v[1])}; }
__device__ __forceinline__ f32x2 frcpv (f32x2 v){ return (f32x2){frcpf(v[0]),  frcpf(v[1])};  }

// packed fp32x2 -> fp16x2 (RTZ), as _Float16 vector
__device__ __forceinline__ half2v pkrtz(float a, float b) {
    fp16x2 r = __builtin_amdgcn_cvt_pkrtz(a, b);
    return __builtin_bit_cast(half2v, r);
}

// exact fp32 -> (hi, lo): hi = v with low 13 mantissa bits cleared (11 sig
// bits -> exact in fp16), lo = v - hi (exact; |lo| <= 2^-11 |v|).
__device__ __forceinline__ float himask(float v) {
    return __builtin_bit_cast(float, __builtin_bit_cast(unsigned int, v) & 0xFFFFE000u);
}

__global__ __launch_bounds__(BLK, 2)
void lstm_mfma_kernel(const float* __restrict__ x,
                      const float* __restrict__ W_ih,   // (160,1)
                      const float* __restrict__ W_hh,   // (160,40) row-major
                      const float* __restrict__ b_ih,   // (160,)
                      const float* __restrict__ b_hh,   // (160,)
                      const float* __restrict__ W_fc,   // (4,40) row-major
                      const float* __restrict__ b_fc,   // (4,)
                      float* __restrict__ out)          // [B*4 logits][B argmax]
{
    __shared__ float lds[WPB * SPW * LROW];

    const int tid  = threadIdx.x;
    const int wv   = __builtin_amdgcn_readfirstlane(tid >> 6);
    const int lane = tid & 63;
    const int col  = lane & 15;        // MFMA m / n index
    const int quad = lane >> 4;        // MFMA k-group / C-row group
    const int sbase = blockIdx.x * SPB + wv * SPW;

    float* hbase = lds + wv * (SPW * LROW);

    // ---------------- prologue: zero LDS slice, bias-one column ----------------
#pragma unroll
    for (int i = 0; i < (SPW * LROW) / 64; ++i)     // 1088/64 = 17
        hbase[i * 64 + lane] = 0.0f;
    if (quad == 0) hbase[col * LROW + 41] = 1.0f;   // h_aug[m][41] = 1.0 (bias)

    // ---------------- prologue: load + scale + fp16-split B fragments ----------
    half8v Bh32[NT], Bl32[NT];
    half4v Bh16[NT], Bl16[NT];
#pragma unroll
    for (int tau = 0; tau < NT; ++tau) {
        const int   tt    = tau / 3;                 // gate type 0:i 1:f 2:g 3:o
        const int   ubase = (tau % 3) * 16;
        const float scale = (tt == 2) ? (2.0f * LOG2E) : (-LOG2E);
        const int   u     = ubase + col;             // padded unit index (0..47)
        const bool  valid = (u < H_);
        const int   r     = tt * H_ + (valid ? u : (H_ - 1));  // clamped row

        {
            float4 w0 = *reinterpret_cast<const float4*>(W_hh + r * H_ + 8 * quad);
            float4 w1 = *reinterpret_cast<const float4*>(W_hh + r * H_ + 8 * quad + 4);
            float wa[8] = {w0.x, w0.y, w0.z, w0.w, w1.x, w1.y, w1.z, w1.w};
            half8v bh, bl;
#pragma unroll
            for (int j = 0; j < 8; ++j) {
                float w = valid ? (wa[j] * scale) : 0.0f;
                _Float16 hi = (_Float16)w;
                bh[j] = hi;
                bl[j] = (_Float16)(w - (float)hi);
            }
            Bh32[tau] = bh; Bl32[tau] = bl;
        }
        {
            float4 wv4;
            if (quad == 0)      wv4 = *reinterpret_cast<const float4*>(W_hh + r * H_ + 32);
            else if (quad == 1) wv4 = *reinterpret_cast<const float4*>(W_hh + r * H_ + 36);
            else if (quad == 2) wv4 = make_float4(W_ih[r], b_ih[r] + b_hh[r], 0.0f, 0.0f);
            else                wv4 = make_float4(0.0f, 0.0f, 0.0f, 0.0f);
            float wa[4] = {wv4.x, wv4.y, wv4.z, wv4.w};
            half4v bh, bl;
#pragma unroll
            for (int j = 0; j < 4; ++j) {
                float w = valid ? (wa[j] * scale) : 0.0f;
                _Float16 hi = (_Float16)w;
                bh[j] = hi;
                bl[j] = (_Float16)(w - (float)hi);
            }
            Bh16[tau] = bh; Bl16[tau] = bl;
        }
    }

    // cell state as r-pairs: cst2[jt][p] = (c[r=2p], c[r=2p+1])
    f32x2 cst2[3][2];
#pragma unroll
    for (int jt = 0; jt < 3; ++jt) {
        cst2[jt][0] = (f32x2){0.f, 0.f};
        cst2[jt][1] = (f32x2){0.f, 0.f};
    }

    const f32x4 zc = (f32x4){0.f, 0.f, 0.f, 0.f};

    // ---------------- t-invariant LDS pointers (immediate-offset accesses) -----
    const float* myrow = hbase + col * LROW;            // A-frag row
    const float* a32p  = myrow + 8 * quad;              // K32 reads: [0..3],[4..7]
    const float* a16p  = myrow + 32 + 4 * quad;         // K16 reads: [0..3]
    float* xslot  = hbase + col * LROW + 40;            // x_t staging (quad 0)
    float* wbase  = hbase + 4 * quad * LROW + col;      // hn stores, jt=0,1
    float* wbase2 = wbase + ((col >= 8) ? 8 : 0);       // hn stores, jt=2 (pad skip)

    const float* xrow = x + (long)(sbase + col) * T_;
    float xv = xrow[0];

    // ---------------- recurrence ----------------
#pragma unroll 1
    for (int t = 0; t < T_; ++t) {
        if (quad == 0) *xslot = xv;
        const int tn = (t + 1 < T_) ? (t + 1) : (T_ - 1);
        const float xnext = xrow[tn];

        // A fragments: mask-split (hi = masked, lo = exact residual), pkrtz pack
        half8v ah32, al32; half4v ah16, al16;
        {
            f32x4 hv0 = *reinterpret_cast<const f32x4*>(a32p);
            f32x4 hv1 = *reinterpret_cast<const f32x4*>(a32p + 4);
            f32x4 hv2 = *reinterpret_cast<const f32x4*>(a16p);

            f32x4 hi0, hi1, hi2;
#pragma unroll
            for (int j = 0; j < 4; ++j) {
                hi0[j] = himask(hv0[j]);
                hi1[j] = himask(hv1[j]);
                hi2[j] = himask(hv2[j]);
            }
            f32x4 lo0 = hv0 - hi0;   // vector sub -> packed-fp32 candidates
            f32x4 lo1 = hv1 - hi1;
            f32x4 lo2 = hv2 - hi2;

            half2v h00 = pkrtz(hi0[0], hi0[1]);
            half2v h01 = pkrtz(hi0[2], hi0[3]);
            half2v h10 = pkrtz(hi1[0], hi1[1]);
            half2v h11 = pkrtz(hi1[2], hi1[3]);
            half2v l00 = pkrtz(lo0[0], lo0[1]);
            half2v l01 = pkrtz(lo0[2], lo0[3]);
            half2v l10 = pkrtz(lo1[0], lo1[1]);
            half2v l11 = pkrtz(lo1[2], lo1[3]);
            half2v h20 = pkrtz(hi2[0], hi2[1]);
            half2v h21 = pkrtz(hi2[2], hi2[3]);
            half2v l20 = pkrtz(lo2[0], lo2[1]);
            half2v l21 = pkrtz(lo2[2], lo2[3]);

            half4v a0 = __builtin_shufflevector(h00, h01, 0, 1, 2, 3);
            half4v a1 = __builtin_shufflevector(h10, h11, 0, 1, 2, 3);
            ah32 = __builtin_shufflevector(a0, a1, 0, 1, 2, 3, 4, 5, 6, 7);
            half4v b0 = __builtin_shufflevector(l00, l01, 0, 1, 2, 3);
            half4v b1 = __builtin_shufflevector(l10, l11, 0, 1, 2, 3);
            al32 = __builtin_shufflevector(b0, b1, 0, 1, 2, 3, 4, 5, 6, 7);
            ah16 = __builtin_shufflevector(h20, h21, 0, 1, 2, 3);
            al16 = __builtin_shufflevector(l20, l21, 0, 1, 2, 3);
        }

        // 3 phases of unit-groups; per phase 4 tiles (i,f,g,o), 6 MFMAs each
#pragma unroll
        for (int jt = 0; jt < 3; ++jt) {
#define DOT48(tau, dst)                                                          \
            {                                                                    \
                f32x4 a = __builtin_amdgcn_mfma_f32_16x16x32_f16(ah32, Bh32[tau], zc, 0, 0, 0); \
                a = __builtin_amdgcn_mfma_f32_16x16x32_f16(al32, Bh32[tau], a, 0, 0, 0); \
                a = __builtin_amdgcn_mfma_f32_16x16x32_f16(ah32, Bl32[tau], a, 0, 0, 0); \
                a = __builtin_amdgcn_mfma_f32_16x16x16f16(ah16, Bh16[tau], a, 0, 0, 0); \
                a = __builtin_amdgcn_mfma_f32_16x16x16f16(al16, Bh16[tau], a, 0, 0, 0); \
                a = __builtin_amdgcn_mfma_f32_16x16x16f16(ah16, Bl16[tau], a, 0, 0, 0); \
                dst = a;                                                         \
            }
            f32x4 ai, af, ag, ao;
            DOT48(jt, ai)
            DOT48(3 + jt, af)
            DOT48(6 + jt, ag)
            DOT48(9 + jt, ao)
#undef DOT48

            // packed activations over r-pairs p = {0,1}: r = 2p, 2p+1
#pragma unroll
            for (int p = 0; p < 2; ++p) {
                const f32x2 yi = (f32x2){ai[2*p], ai[2*p+1]};
                const f32x2 yf = (f32x2){af[2*p], af[2*p+1]};
                const f32x2 yg = (f32x2){ag[2*p], ag[2*p+1]};
                const f32x2 yo = (f32x2){ao[2*p], ao[2*p+1]};
                // merged-rcp algebra (identical elementwise ops to R12):
                //   cn = [c(1+e_i)(1+E_g) + (E_g-1)(1+e_f)] / [(1+e_i)(1+E_g)(1+e_f)]
                //   hn = (E_c-1) / [(1+e_o)(1+E_c)]
                const f32x2 ei = fexp2v(yi);
                const f32x2 ef = fexp2v(yf);
                const f32x2 Eg = fexp2v(yg);
                const f32x2 eo = fexp2v(yo);
                const f32x2 one = (f32x2){1.0f, 1.0f};
                const f32x2 u_ = one + ei;
                const f32x2 v_ = one + Eg;
                const f32x2 w_ = one + ef;
                const f32x2 p_ = u_ * v_;
                const f32x2 q_ = (Eg - one) * w_;
                const f32x2 num = cst2[jt][p] * p_ + q_;       // pk_fma
                const f32x2 cn  = num * frcpv(p_ * w_);
                cst2[jt][p] = cn;
                const f32x2 Ec = fexp2v(cn * (f32x2){2.0f*LOG2E, 2.0f*LOG2E});
                const f32x2 hn = (Ec - one) * frcpv((one + eo) * (one + Ec));
                // immediate-offset stores (jt, p compile-time after unroll)
                if (jt < 2) {
                    wbase [(2*p)   * LROW + jt * 16] = hn[0];
                    wbase [(2*p+1) * LROW + jt * 16] = hn[1];
                } else {
                    wbase2[(2*p)   * LROW + 32]      = hn[0];
                    wbase2[(2*p+1) * LROW + 32]      = hn[1];
                }
            }
        }

        xv = xnext;
    }

    // ---------------- epilogue: FC + argmax ----------------
    {
        float acc = b_fc[quad];
#pragma unroll
        for (int jj = 0; jj < 10; ++jj) {
            f32x4 hv = *reinterpret_cast<const f32x4*>(myrow + 4 * jj);
            float4 wv4 = *reinterpret_cast<const float4*>(W_fc + quad * H_ + 4 * jj);
            acc = fmaf(hv[0], wv4.x, acc);
            acc = fmaf(hv[1], wv4.y, acc);
            acc = fmaf(hv[2], wv4.z, acc);
            acc = fmaf(hv[3], wv4.w, acc);
        }
        out[(long)(sbase + col) * C_ + quad] = acc;
        hbase[col * LROW + 56 + quad] = acc;   // scratch for argmax
    }
    if (quad == 0) {
        f32x4 lg = *reinterpret_cast<const f32x4*>(hbase + col * LROW + 56);
        int am = 0;
        float best = lg[0];
        if (lg[1] > best) { best = lg[1]; am = 1; }
        if (lg[2] > best) { best = lg[2]; am = 2; }
        if (lg[3] > best) { best = lg[3]; am = 3; }
        out[(long)B_ * C_ + sbase + col] = (float)am;
    }
}

extern "C" void kernel_launch(void* const* d_in, const int* in_sizes, int n_in,
                              void* d_out, int out_size, void* d_ws, size_t ws_size,
                              hipStream_t stream) {
    const float* x    = (const float*)d_in[0];
    const float* W_ih = (const float*)d_in[1];
    const float* W_hh = (const float*)d_in[2];
    const float* b_ih = (const float*)d_in[3];
    const float* b_hh = (const float*)d_in[4];
    const float* W_fc = (const float*)d_in[5];
    const float* b_fc = (const float*)d_in[6];
    float* out = (float*)d_out;

    dim3 block(BLK);
    dim3 grid(B_ / SPB);
    hipLaunchKernelGGL(lstm_mfma_kernel, grid, block, 0, stream,
                       x, W_ih, W_hh, b_ih, b_hh, W_fc, b_fc, out);
}